// Round 1
// baseline (469.154 us; speedup 1.0000x reference)
//
#include <hip/hip_runtime.h>

#define HWSZ 16384
#define CIN 96
#define ICTOT 288
#define OCTOT 288
#define KTOT 2592
#define OUT_S_ELEMS (8*96*16384)

typedef __attribute__((ext_vector_type(8))) short bf16x8;
typedef __attribute__((ext_vector_type(4))) float f32x4;

__device__ __forceinline__ unsigned short f2bf(float f){
  unsigned int u = __float_as_uint(f);
  u += 0x7FFFu + ((u >> 16) & 1u);
  return (unsigned short)(u >> 16);
}
__device__ __forceinline__ float bf2f(unsigned short s){
  return __uint_as_float(((unsigned int)s) << 16);
}

// ---- build combined filter Wb[oc][k], k = tap*288 + ic, bf16 ----
__global__ void pack_w_kernel(const float* __restrict__ w_ss, const float* __restrict__ w_sv,
                              const float* __restrict__ w_vs, const float* __restrict__ w_vv,
                              const float* __restrict__ f_k0, const float* __restrict__ f_k1,
                              const float* __restrict__ f_k2, unsigned short* __restrict__ Wb){
  int idx = blockIdx.x*256 + threadIdx.x;
  if (idx >= OCTOT*KTOT) return;
  int oc = idx / KTOT, k = idx - oc*KTOT;
  int tap = k / ICTOT, ic = k - tap*ICTOT;
  float acc = 0.f;
  if (oc < 96){
    int o = oc;
    if (ic < CIN){
      int i = ic;
      for (int n=0;n<3;++n) acc += w_ss[(o*CIN+i)*3+n]*f_k0[n*9+tap];
    } else {
      int v = ic-CIN; int i=v>>1, a=v&1;
      for (int n=0;n<4;++n) acc += w_vs[(o*CIN+i)*4+n]*f_k1[(n*9+tap)*2+a];
    }
  } else {
    int ov = oc-96; int o=ov>>1, c=ov&1;
    if (ic < CIN){
      int i = ic;
      for (int n=0;n<4;++n) acc += w_sv[(o*CIN+i)*4+n]*f_k1[(n*9+tap)*2+c];
    } else {
      int v = ic-CIN; int i=v>>1, a=v&1;
      for (int n=0;n<5;++n) acc += w_vv[(o*CIN+i)*5+n]*f_k2[((n*9+tap)*2+a)*2+c];
    }
  }
  Wb[idx] = f2bf(acc);
}

// ---- pack x_scalar -> Xp[b][p][ic] (ic 0..95), bf16, tiled transpose ----
__global__ void pack_xs_kernel(const float* __restrict__ xs, unsigned short* __restrict__ Xp){
  __shared__ float tile[32][65];
  int bid = blockIdx.x;
  int ct = bid % 3; int pt = (bid/3) & 255; int b = bid / 768;
  int p0 = pt*64, c0 = ct*32;
  int t = threadIdx.x;
  int cl = t >> 6, pl = t & 63;
  for (int kk=0; kk<8; ++kk){
    int c = kk*4 + cl;
    tile[c][pl] = xs[(size_t)(b*CIN + c0 + c)*HWSZ + p0 + pl];
  }
  __syncthreads();
  int c = t & 31, pw = t >> 5;
  for (int j=0;j<8;++j){
    int p = pw*8 + j;
    Xp[(size_t)(b*HWSZ + p0 + p)*ICTOT + c0 + c] = f2bf(tile[c][p]);
  }
}

// ---- pack x_vector -> Xp[b][p][96 + 2i + a], bf16 pairs ----
__global__ void pack_xv_kernel(const float* __restrict__ xv, unsigned short* __restrict__ Xp){
  __shared__ float2 tile[32][65];
  int bid = blockIdx.x;
  int ct = bid % 3; int pt = (bid/3) & 255; int b = bid / 768;
  int p0 = pt*64, c0 = ct*32;
  int t = threadIdx.x;
  int cl = t >> 6, pl = t & 63;
  const float2* src = (const float2*)xv;
  for (int kk=0; kk<8; ++kk){
    int c = kk*4 + cl;
    tile[c][pl] = src[(size_t)(b*CIN + c0 + c)*HWSZ + p0 + pl];
  }
  __syncthreads();
  int c = t & 31, pw = t >> 5;
  for (int j=0;j<8;++j){
    int p = pw*8 + j;
    float2 v = tile[c][p];
    unsigned int u = (unsigned int)f2bf(v.x) | ((unsigned int)f2bf(v.y) << 16);
    *(unsigned int*)&Xp[(size_t)(b*HWSZ + p0 + p)*ICTOT + CIN + 2*(c0+c)] = u;
  }
}

// ---- implicit-GEMM conv: tile 96(oc) x 128(one pixel row), BK=32, 81 K-steps ----
__global__ __launch_bounds__(256,2) void conv_mfma_kernel(
    const unsigned short* __restrict__ Xp, const unsigned short* __restrict__ Wb,
    const float* __restrict__ b_s, float* __restrict__ out, float* __restrict__ sums){
  __shared__ unsigned short As[96][40];   // pad stride 40 -> 2-way bank alias (free)
  __shared__ unsigned short Bs[128][40];
  int bid = blockIdx.x;
  int mt = bid % 3; int rest = bid/3; int h = rest & 127; int b = rest >> 7;
  int tid = threadIdx.x;
  int lane = tid & 63, wv = tid >> 6;
  int wr = wv >> 1, wc = wv & 1;
  int cl = lane & 15, g = lane >> 4;

  f32x4 acc[3][4];
  #pragma unroll
  for (int m=0;m<3;++m)
    #pragma unroll
    for (int n=0;n<4;++n) acc[m][n] = (f32x4){0.f,0.f,0.f,0.f};

  int bw = tid >> 1;            // 0..127 : output-row pixel this thread stages
  int ko = (tid & 1) * 16;      // 0 or 16 within the 32-wide K chunk
  int am = tid >> 1;            // 0..95 for tid<192
  bool doA = (tid < 192);

  uint4 rb0, rb1, ra0, ra1;
  const size_t xb = (size_t)b * HWSZ * ICTOT;

  { // prologue: step 0 = (tap 0 -> ky=0,kx=0 ; icc 0)
    int hh = (h - 1 + 128) & 127;
    int wwp = (bw - 1 + 128) & 127;
    const uint4* srcB = (const uint4*)(Xp + xb + (size_t)(hh*128 + wwp)*ICTOT + ko);
    rb0 = srcB[0]; rb1 = srcB[1];
    if (doA){
      const uint4* srcA = (const uint4*)(Wb + (size_t)(mt*96 + am)*KTOT + ko);
      ra0 = srcA[0]; ra1 = srcA[1];
    }
  }
  int tapn = 0, iccn = 1;
  for (int s=0; s<81; ++s){
    __syncthreads();                 // prior frag reads done before overwrite
    *(uint4*)&Bs[bw][ko]   = rb0;
    *(uint4*)&Bs[bw][ko+8] = rb1;
    if (doA){
      *(uint4*)&As[am][ko]   = ra0;
      *(uint4*)&As[am][ko+8] = ra1;
    }
    if (s+1 < 81){                   // issue next-step loads; in flight during MFMA
      int ky = tapn/3, kx = tapn - ky*3;
      int hh = (h + ky - 1 + 128) & 127;
      int wwp = (bw + kx - 1 + 128) & 127;
      const uint4* srcB = (const uint4*)(Xp + xb + (size_t)(hh*128 + wwp)*ICTOT + iccn*32 + ko);
      rb0 = srcB[0]; rb1 = srcB[1];
      if (doA){
        const uint4* srcA = (const uint4*)(Wb + (size_t)(mt*96 + am)*KTOT + (s+1)*32 + ko);
        ra0 = srcA[0]; ra1 = srcA[1];
      }
      ++iccn; if (iccn == 9){ iccn = 0; ++tapn; }
    }
    __syncthreads();                 // LDS ready
    bf16x8 af[3], bfr[4];
    #pragma unroll
    for (int m=0;m<3;++m) af[m] = *(const bf16x8*)&As[wr*48 + m*16 + cl][g*8];
    #pragma unroll
    for (int n=0;n<4;++n) bfr[n] = *(const bf16x8*)&Bs[wc*64 + n*16 + cl][g*8];
    #pragma unroll
    for (int m=0;m<3;++m)
      #pragma unroll
      for (int n=0;n<4;++n)
        acc[m][n] = __builtin_amdgcn_mfma_f32_16x16x32_bf16(af[m], bfr[n], acc[m][n], 0,0,0);
  }

  if (mt == 0){
    // scalar outputs, rows = oc 0..95 ; D mapping: col=lane&15, row=4*(lane>>4)+r
    #pragma unroll
    for (int m=0;m<3;++m){
      #pragma unroll
      for (int r=0;r<4;++r){
        int oc = wr*48 + m*16 + 4*g + r;
        float bias = b_s[oc];
        #pragma unroll
        for (int n=0;n<4;++n){
          int p = h*128 + wc*64 + n*16 + cl;
          out[(size_t)(b*96+oc)*HWSZ + p] = acc[m][n][r] + bias;
        }
      }
    }
  } else {
    float2* outv = (float2*)(out + OUT_S_ELEMS);
    int base = (mt-1)*96 + wr*48;
    #pragma unroll
    for (int m=0;m<3;++m){
      int row0 = base + m*16 + 4*g;   // even; rows are (o,c) pairs: oc_v = 2o+c
      int o0 = row0 >> 1;
      #pragma unroll
      for (int n=0;n<4;++n){
        int p = h*128 + wc*64 + n*16 + cl;
        float2 v01 = {acc[m][n][0], acc[m][n][1]};
        float2 v23 = {acc[m][n][2], acc[m][n][3]};
        outv[(size_t)(b*96+o0  )*HWSZ + p] = v01;
        outv[(size_t)(b*96+o0+1)*HWSZ + p] = v23;
      }
      #pragma unroll
      for (int r=0;r<4;++r){
        float part = acc[m][0][r]+acc[m][1][r]+acc[m][2][r]+acc[m][3][r];
        part += __shfl_xor(part, 1);
        part += __shfl_xor(part, 2);
        part += __shfl_xor(part, 4);
        part += __shfl_xor(part, 8);
        if (cl == 0) atomicAdd(&sums[b*192 + row0 + r], part);
      }
    }
  }
}

// ---- out_v += b_v * mean(out_v over H,W) ----
__global__ void bias_v_kernel(float* __restrict__ out, const float* __restrict__ sums,
                              const float* __restrict__ b_v){
  int bo = blockIdx.x;               // 0..767
  int b = bo / 96, o = bo % 96;
  float bv = b_v[o];
  float ax = bv * sums[b*192 + 2*o    ] * (1.f/16384.f);
  float ay = bv * sums[b*192 + 2*o + 1] * (1.f/16384.f);
  float2* p = (float2*)(out + OUT_S_ELEMS) + (size_t)(b*96+o)*HWSZ;
  for (int i = threadIdx.x; i < HWSZ; i += 256){
    float2 v = p[i]; v.x += ax; v.y += ay; p[i] = v;
  }
}

// ---- fallback if workspace too small for Xp: direct conv from NCHW fp32 ----
__global__ void naive_conv_kernel(const float* __restrict__ xs, const float* __restrict__ xv,
    const unsigned short* __restrict__ Wb, const float* __restrict__ b_s,
    float* __restrict__ out, float* __restrict__ sums){
  int bid = blockIdx.x;
  int h = bid & 127; int o = (bid >> 7) % 96; int b = bid / (96*128);
  int w = threadIdx.x;               // 128 threads
  float aS=0.f, a0=0.f, a1=0.f;
  const float2* xv2 = (const float2*)xv;
  for (int tap=0; tap<9; ++tap){
    int ky = tap/3, kx = tap - ky*3;
    int hh = (h + ky - 1 + 128) & 127;
    int ww2 = (w + kx - 1 + 128) & 127;
    const unsigned short* Ws = Wb + (size_t)o*KTOT + tap*ICTOT;
    const unsigned short* W0 = Wb + (size_t)(96 + 2*o)*KTOT + tap*ICTOT;
    const unsigned short* W1 = W0 + KTOT;
    const float* xrow = xs + ((size_t)(b*96)*128 + hh)*128 + ww2;
    for (int i=0;i<96;++i){
      float xval = xrow[(size_t)i*HWSZ];
      aS += xval*bf2f(Ws[i]); a0 += xval*bf2f(W0[i]); a1 += xval*bf2f(W1[i]);
    }
    const float2* vrow = xv2 + ((size_t)(b*96)*128 + hh)*128 + ww2;
    for (int i=0;i<96;++i){
      float2 xx = vrow[(size_t)i*HWSZ];
      int ic = 96 + 2*i;
      aS += xx.x*bf2f(Ws[ic]) + xx.y*bf2f(Ws[ic+1]);
      a0 += xx.x*bf2f(W0[ic]) + xx.y*bf2f(W0[ic+1]);
      a1 += xx.x*bf2f(W1[ic]) + xx.y*bf2f(W1[ic+1]);
    }
  }
  size_t pix = (size_t)h*128 + w;
  out[(size_t)(b*96+o)*HWSZ + pix] = aS + b_s[o];
  float2* outv = (float2*)(out + OUT_S_ELEMS);
  outv[(size_t)(b*96+o)*HWSZ + pix] = (float2){a0, a1};
  float r0 = a0, r1 = a1;
  for (int m=1; m<64; m<<=1){ r0 += __shfl_xor(r0, m); r1 += __shfl_xor(r1, m); }
  __shared__ float red[4];
  int lane = w & 63, wvv = w >> 6;
  if (lane == 0){ red[wvv*2] = r0; red[wvv*2+1] = r1; }
  __syncthreads();
  if (w == 0){
    atomicAdd(&sums[b*192 + 2*o],     red[0] + red[2]);
    atomicAdd(&sums[b*192 + 2*o + 1], red[1] + red[3]);
  }
}

extern "C" void kernel_launch(void* const* d_in, const int* in_sizes, int n_in,
                              void* d_out, int out_size, void* d_ws, size_t ws_size,
                              hipStream_t stream){
  const float* xs   = (const float*)d_in[0];
  const float* xv   = (const float*)d_in[1];
  const float* f_k0 = (const float*)d_in[2];
  const float* f_k1 = (const float*)d_in[3];
  const float* f_k2 = (const float*)d_in[4];
  const float* w_ss = (const float*)d_in[5];
  const float* w_sv = (const float*)d_in[6];
  const float* w_vs = (const float*)d_in[7];
  const float* w_vv = (const float*)d_in[8];
  const float* b_s  = (const float*)d_in[9];
  const float* b_v  = (const float*)d_in[10];
  float* out = (float*)d_out;

  char* ws = (char*)d_ws;
  float* sums = (float*)ws;                                  // 6144 B used
  unsigned short* Wb = (unsigned short*)(ws + 8192);         // 1,492,992 B
  const size_t XP_OFF = 1501184;                             // 16B aligned
  unsigned short* Xp = (unsigned short*)(ws + XP_OFF);
  const size_t NEED = XP_OFF + (size_t)8*HWSZ*ICTOT*2;       // ~77 MB

  hipMemsetAsync(sums, 0, 8*192*sizeof(float), stream);
  pack_w_kernel<<<(OCTOT*KTOT+255)/256, 256, 0, stream>>>(w_ss, w_sv, w_vs, w_vv,
                                                          f_k0, f_k1, f_k2, Wb);
  if (ws_size >= NEED){
    pack_xs_kernel<<<6144, 256, 0, stream>>>(xs, Xp);
    pack_xv_kernel<<<6144, 256, 0, stream>>>(xv, Xp);
    conv_mfma_kernel<<<3072, 256, 0, stream>>>(Xp, Wb, b_s, out, sums);
  } else {
    naive_conv_kernel<<<8*96*128, 128, 0, stream>>>(xs, xv, Wb, b_s, out, sums);
  }
  bias_v_kernel<<<768, 256, 0, stream>>>(out, sums, b_v);
}

// Round 2
// 302.572 us; speedup vs baseline: 1.5506x; 1.5506x over previous
//
#include <hip/hip_runtime.h>

#define HWSZ 16384
#define CIN 96
#define ICTOT 288
#define OUT_S_ELEMS (8*96*16384)
#define TILE_USH (ICTOT*32)          // 9216 ushorts = 18432 B per A k-tile
#define NTILES 81

typedef __attribute__((ext_vector_type(8))) short bf16x8;
typedef __attribute__((ext_vector_type(4))) float f32x4;

#define VMCNT(n) asm volatile("s_waitcnt vmcnt(" #n ")" ::: "memory")
#define LGKM0    asm volatile("s_waitcnt lgkmcnt(0)" ::: "memory")

__device__ __forceinline__ unsigned short f2bf(float f){
  unsigned int u = __float_as_uint(f);
  u += 0x7FFFu + ((u >> 16) & 1u);
  return (unsigned short)(u >> 16);
}

__device__ __forceinline__ void gload16(const unsigned short* g, const unsigned short* l){
  __builtin_amdgcn_global_load_lds(
      (const __attribute__((address_space(1))) unsigned int*)g,
      (__attribute__((address_space(3))) unsigned int*)l, 16, 0, 0);
}

// ---- build filter tiles WbT[j][oc][cc], j = chunk*9 + tap, k = tap*288 + chunk*32 + cc ----
__global__ void pack_w_kernel(const float* __restrict__ w_ss, const float* __restrict__ w_sv,
                              const float* __restrict__ w_vs, const float* __restrict__ w_vv,
                              const float* __restrict__ f_k0, const float* __restrict__ f_k1,
                              const float* __restrict__ f_k2, unsigned short* __restrict__ WbT){
  int idx = blockIdx.x*256 + threadIdx.x;
  if (idx >= NTILES*ICTOT*32) return;
  int j = idx / (ICTOT*32); int rem = idx - j*(ICTOT*32);
  int oc = rem >> 5, cc = rem & 31;
  int tap = j % 9, cch = j / 9;
  int ic = cch*32 + cc;
  float acc = 0.f;
  if (oc < 96){
    int o = oc;
    if (ic < CIN){
      int i = ic;
      for (int n=0;n<3;++n) acc += w_ss[(o*CIN+i)*3+n]*f_k0[n*9+tap];
    } else {
      int v = ic-CIN; int i=v>>1, a=v&1;
      for (int n=0;n<4;++n) acc += w_vs[(o*CIN+i)*4+n]*f_k1[(n*9+tap)*2+a];
    }
  } else {
    int ov = oc-96; int o=ov>>1, c=ov&1;
    if (ic < CIN){
      int i = ic;
      for (int n=0;n<4;++n) acc += w_sv[(o*CIN+i)*4+n]*f_k1[(n*9+tap)*2+c];
    } else {
      int v = ic-CIN; int i=v>>1, a=v&1;
      for (int n=0;n<5;++n) acc += w_vv[(o*CIN+i)*5+n]*f_k2[((n*9+tap)*2+a)*2+c];
    }
  }
  WbT[(size_t)j*TILE_USH + oc*32 + cc] = f2bf(acc);
}

// ---- pack x_scalar -> Xp[b][p][ic] (ic 0..95), bf16, tiled transpose ----
__global__ void pack_xs_kernel(const float* __restrict__ xs, unsigned short* __restrict__ Xp){
  __shared__ float tile[32][65];
  int bid = blockIdx.x;
  int ct = bid % 3; int pt = (bid/3) & 255; int b = bid / 768;
  int p0 = pt*64, c0 = ct*32;
  int t = threadIdx.x;
  int cl = t >> 6, pl = t & 63;
  for (int kk=0; kk<8; ++kk){
    int c = kk*4 + cl;
    tile[c][pl] = xs[(size_t)(b*CIN + c0 + c)*HWSZ + p0 + pl];
  }
  __syncthreads();
  int c = t & 31, pw = t >> 5;
  for (int j=0;j<8;++j){
    int p = pw*8 + j;
    Xp[(size_t)(b*HWSZ + p0 + p)*ICTOT + c0 + c] = f2bf(tile[c][p]);
  }
}

// ---- pack x_vector -> Xp[b][p][96 + 2i + a] ----
__global__ void pack_xv_kernel(const float* __restrict__ xv, unsigned short* __restrict__ Xp){
  __shared__ float2 tile[32][65];
  int bid = blockIdx.x;
  int ct = bid % 3; int pt = (bid/3) & 255; int b = bid / 768;
  int p0 = pt*64, c0 = ct*32;
  int t = threadIdx.x;
  int cl = t >> 6, pl = t & 63;
  const float2* src = (const float2*)xv;
  for (int kk=0; kk<8; ++kk){
    int c = kk*4 + cl;
    tile[c][pl] = src[(size_t)(b*CIN + c0 + c)*HWSZ + p0 + pl];
  }
  __syncthreads();
  int c = t & 31, pw = t >> 5;
  for (int j=0;j<8;++j){
    int p = pw*8 + j;
    float2 v = tile[c][p];
    unsigned int u = (unsigned int)f2bf(v.x) | ((unsigned int)f2bf(v.y) << 16);
    *(unsigned int*)&Xp[(size_t)(b*HWSZ + p0 + p)*ICTOT + CIN + 2*(c0+c)] = u;
  }
}

// ---- conv: block = 288 oc x 256 px (2 image rows), 8 waves, 81 K-phases ----
// A: triple-buffered LDS k-tiles (prefetch 2 ahead); B: 4 halo rows x 128 x 32ch
// per channel-chunk, double-buffered, reused across all 9 taps.
__global__ __launch_bounds__(512,2) void conv_mfma_kernel(
    const unsigned short* __restrict__ Xp, const unsigned short* __restrict__ WbT,
    const float* __restrict__ b_s, float* __restrict__ out, float* __restrict__ sums){
  __shared__ unsigned short Ash[3][1536*8];   // 3 x 24576 B (top 6KB = overread slop, never frag-read)
  __shared__ unsigned short Bsh[2][2048*8];   // 2 x 32768 B

  int bid = blockIdx.x;
  int b = bid & 7, rp = bid >> 3;             // batch -> XCD, row-pair 0..63
  int tid = threadIdx.x;
  int lane = tid & 63, w = tid >> 6;
  int wr = w >> 2, wc = w & 3;                // wave tile: 144 oc x 64 px
  int cl = lane & 15, g = lane >> 4;

  f32x4 acc[9][4];
  #pragma unroll
  for (int m=0;m<9;++m)
    #pragma unroll
    for (int n=0;n<4;++n) acc[m][n] = (f32x4){0.f,0.f,0.f,0.f};

  // B-stage source pointers: chunk f = i*512+tid -> (halo row j, px, 8ch-part)
  const size_t xb = (size_t)b * HWSZ * ICTOT;
  const unsigned short* srcB[4];
  #pragma unroll
  for (int i=0;i<4;++i){
    int f = i*512 + tid;
    int j = f >> 9, px = (f >> 2) & 127, cp = f & 3;
    int hs = (2*rp - 1 + j + 128) & 127;
    srcB[i] = Xp + xb + ((size_t)(hs*128 + px))*ICTOT + cp*8;
  }
  const unsigned short* srcA = WbT + tid*8;
  const int wlds = w*64*8;                    // wave-uniform LDS chunk base (ushorts)
  const int Abase = (wr*144 + cl)*32 + g*8;   // A frag lane addr (ushorts), +m*512
  const int pxb = (wc & 1)*64 + cl;
  const int jr0 = (wc >> 1);

  // prologue: B(0), A(0), A(1)  (order matters for vmcnt accounting)
  #pragma unroll
  for (int i=0;i<4;++i) gload16(srcB[i], &Bsh[0][i*512*8 + wlds]);
  #pragma unroll
  for (int i=0;i<3;++i) gload16(srcA,               &Ash[0][i*512*8 + wlds] - i*0 + (i*512*8)*0), // placeholder avoided below
  (void)0;
  #pragma unroll
  for (int i=0;i<3;++i) gload16(srcA + 0*TILE_USH + i*4096, &Ash[0][i*512*8 + wlds]);
  #pragma unroll
  for (int i=0;i<3;++i) gload16(srcA + 1*TILE_USH + i*4096, &Ash[1][i*512*8 + wlds]);
  VMCNT(3);                                   // B(0), A(0) landed; A(1) in flight
  __builtin_amdgcn_s_barrier();

  const unsigned short* cA = srcA;            // advances 9 tiles per chunk iter
  for (int c = 0; c < 9; ++c){
    const unsigned short* Bcur = Bsh[c & 1];
    unsigned short* Bnxt = (unsigned short*)Bsh[(c & 1) ^ 1];
    #pragma unroll
    for (int t = 0; t < 9; ++t){
      // issue A(s+2) first, then B(c+1) (at t==0) — ordering fixes vmcnt math
      if (c < 8 || t <= 6){
        #pragma unroll
        for (int i=0;i<3;++i)
          gload16(cA + (t+2)*TILE_USH + i*4096, &Ash[(t+2)%3][i*512*8 + wlds]);
      }
      if (t == 0 && c < 8){
        #pragma unroll
        for (int i=0;i<4;++i)
          gload16(srcB[i] + (c+1)*32, &Bnxt[i*512*8 + wlds]);
      }
      const int ky = t / 3, kx = t % 3;
      const int jbase = (jr0 + ky)*4096;      // halo-row base (ushorts)
      bf16x8 bfr[4];
      #pragma unroll
      for (int n=0;n<4;++n){
        int px = (pxb + n*16 + kx + 127) & 127;
        bfr[n] = *(const bf16x8*)&Bcur[jbase + px*32 + g*8];
      }
      const unsigned short* At = Ash[t % 3];
      __builtin_amdgcn_s_setprio(1);
      #pragma unroll
      for (int m=0;m<9;++m){
        bf16x8 af = *(const bf16x8*)&At[Abase + m*512];
        #pragma unroll
        for (int n=0;n<4;++n)
          acc[m][n] = __builtin_amdgcn_mfma_f32_16x16x32_bf16(af, bfr[n], acc[m][n], 0,0,0);
      }
      __builtin_amdgcn_s_setprio(0);
      LGKM0;                                  // my frag reads retired
      if (t <= 1){ if (c < 8) { VMCNT(7); } else { VMCNT(3); } }
      else if (t >= 7){ if (c == 8) { VMCNT(0); } else { VMCNT(3); } }
      else { VMCNT(3); }
      __builtin_amdgcn_sched_barrier(0);
      __builtin_amdgcn_s_barrier();
    }
    cA += 9*TILE_USH;
  }

  // epilogue
  const int orow = 2*rp + (wc >> 1);
  const int colb = (wc & 1)*64;
  #pragma unroll
  for (int m=0;m<9;++m){
    int ocb = wr*144 + m*16 + 4*g;            // rows ocb..ocb+3
    if (wr == 0 && m < 6){
      #pragma unroll
      for (int r=0;r<4;++r){
        int oc = ocb + r;
        float bias = b_s[oc];
        #pragma unroll
        for (int n=0;n<4;++n){
          int p = orow*128 + colb + n*16 + cl;
          out[(size_t)(b*96+oc)*HWSZ + p] = acc[m][n][r] + bias;
        }
      }
    } else {
      float2* outv = (float2*)(out + OUT_S_ELEMS);
      int row0 = ocb - 96;                    // even
      int o0 = row0 >> 1;
      #pragma unroll
      for (int n=0;n<4;++n){
        int p = orow*128 + colb + n*16 + cl;
        outv[(size_t)(b*96+o0  )*HWSZ + p] = (float2){acc[m][n][0], acc[m][n][1]};
        outv[(size_t)(b*96+o0+1)*HWSZ + p] = (float2){acc[m][n][2], acc[m][n][3]};
      }
      #pragma unroll
      for (int r=0;r<4;++r){
        float part = acc[m][0][r]+acc[m][1][r]+acc[m][2][r]+acc[m][3][r];
        part += __shfl_xor(part, 1);
        part += __shfl_xor(part, 2);
        part += __shfl_xor(part, 4);
        part += __shfl_xor(part, 8);
        if (cl == 0) atomicAdd(&sums[b*192 + row0 + r], part);
      }
    }
  }
}

// ---- out_v += b_v * mean(out_v over H,W) ----
__global__ void bias_v_kernel(float* __restrict__ out, const float* __restrict__ sums,
                              const float* __restrict__ b_v){
  int bo = blockIdx.x;
  int b = bo / 96, o = bo % 96;
  float bv = b_v[o];
  float ax = bv * sums[b*192 + 2*o    ] * (1.f/16384.f);
  float ay = bv * sums[b*192 + 2*o + 1] * (1.f/16384.f);
  float2* p = (float2*)(out + OUT_S_ELEMS) + (size_t)(b*96+o)*HWSZ;
  for (int i = threadIdx.x; i < HWSZ; i += 256){
    float2 v = p[i]; v.x += ax; v.y += ay; p[i] = v;
  }
}

extern "C" void kernel_launch(void* const* d_in, const int* in_sizes, int n_in,
                              void* d_out, int out_size, void* d_ws, size_t ws_size,
                              hipStream_t stream){
  const float* xs   = (const float*)d_in[0];
  const float* xv   = (const float*)d_in[1];
  const float* f_k0 = (const float*)d_in[2];
  const float* f_k1 = (const float*)d_in[3];
  const float* f_k2 = (const float*)d_in[4];
  const float* w_ss = (const float*)d_in[5];
  const float* w_sv = (const float*)d_in[6];
  const float* w_vs = (const float*)d_in[7];
  const float* w_vv = (const float*)d_in[8];
  const float* b_s  = (const float*)d_in[9];
  const float* b_v  = (const float*)d_in[10];
  float* out = (float*)d_out;

  char* ws = (char*)d_ws;
  unsigned short* WbT = (unsigned short*)ws;                 // 81*18432 B (+6144 overread slop)
  const size_t XP_OFF = (size_t)NTILES*TILE_USH*2 + 6144;    // 1,499,136
  unsigned short* Xp = (unsigned short*)(ws + XP_OFF);
  const size_t SUMS_OFF = XP_OFF + (size_t)8*HWSZ*ICTOT*2;   // + 75,497,472
  float* sums = (float*)(ws + SUMS_OFF);

  hipMemsetAsync(sums, 0, 8*192*sizeof(float), stream);
  pack_w_kernel<<<(NTILES*ICTOT*32 + 255)/256, 256, 0, stream>>>(
      w_ss, w_sv, w_vs, w_vv, f_k0, f_k1, f_k2, WbT);
  pack_xs_kernel<<<6144, 256, 0, stream>>>(xs, Xp);
  pack_xv_kernel<<<6144, 256, 0, stream>>>(xv, Xp);
  conv_mfma_kernel<<<512, 512, 0, stream>>>(Xp, WbT, b_s, out, sums);
  bias_v_kernel<<<768, 256, 0, stream>>>(out, sums, b_v);
}